// Round 20
// baseline (253.668 us; speedup 1.0000x reference)
//
#include <hip/hip_runtime.h>
#include <hip/hip_bf16.h>
#include <hip/hip_fp16.h>
#include <math.h>

#define BB 8
#define DD 256
#define LL 2048
#define KK 24
#define RR 1025
#define HH 512

typedef __attribute__((ext_vector_type(8))) _Float16 f16x8;
typedef __attribute__((ext_vector_type(4))) float f32x4;

__device__ __forceinline__ unsigned short f2h(float f) {
  return __builtin_bit_cast(unsigned short, __float2half_rn(f));
}

// ---------------- LayerNorm over channel dim D, per (b,l) ----------------
__global__ void ln_kernel(const float* __restrict__ x, const float* __restrict__ gamma,
                          const float* __restrict__ beta, float* __restrict__ z) {
  __shared__ float red[2][4][64];
  __shared__ float mu_s[64], rs_s[64];
  int blk = blockIdx.x;
  int b = blk >> 5;
  int l0 = (blk & 31) << 6;
  int t = threadIdx.x;
  int ll = t & 63;
  int part = t >> 6;
  int l = l0 + ll;
  const float* xb = x + ((size_t)b * DD) * LL + l;
  float xv[64];
  float s = 0.f, ss = 0.f;
  #pragma unroll
  for (int i = 0; i < 64; ++i) {
    float v = xb[(size_t)(part * 64 + i) * LL];
    xv[i] = v; s += v; ss += v * v;
  }
  red[0][part][ll] = s; red[1][part][ll] = ss;
  __syncthreads();
  if (part == 0) {
    float S = red[0][0][ll] + red[0][1][ll] + red[0][2][ll] + red[0][3][ll];
    float Q = red[1][0][ll] + red[1][1][ll] + red[1][2][ll] + red[1][3][ll];
    float mu = S * (1.f / 256.f);
    float var = Q * (1.f / 256.f) - mu * mu;
    mu_s[ll] = mu; rs_s[ll] = rsqrtf(var + 1e-5f);
  }
  __syncthreads();
  float mu = mu_s[ll], rs = rs_s[ll];
  float* zb = z + ((size_t)b * DD) * LL + l;
  #pragma unroll
  for (int i = 0; i < 64; ++i) {
    int d = part * 64 + i;
    zb[(size_t)d * LL] = (xv[i] - mu) * rs * gamma[d] + beta[d];
  }
}

// ---------------- Theta -> f16 A2[h][k*256+d] ----------------
__global__ void theta_prep(const float* __restrict__ Theta, unsigned* __restrict__ A2u) {
  int bi = blockIdx.x;
  int k = bi >> 8, h = bi & 255;
  int t = threadIdx.x;   // 0..127, d = 2t
  float2 v = *reinterpret_cast<const float2*>(Theta + (size_t)k * 65536 + h * 256 + 2 * t);
  A2u[(size_t)h * 3072 + k * 128 + t] =
      __builtin_bit_cast(unsigned, __floats2half2_rn(v.x, v.y));
}

// ---------------- W1/W2 -> f16 (same layouts) ----------------
__global__ void w_prep(const float* __restrict__ W1, const float* __restrict__ W2,
                       unsigned* __restrict__ W1h, unsigned* __restrict__ W2h) {
  int i = blockIdx.x * 256 + threadIdx.x;        // 0..65535, pairs
  float2 a = reinterpret_cast<const float2*>(W1)[i];
  W1h[i] = __builtin_bit_cast(unsigned, __floats2half2_rn(a.x, a.y));
  float2 b = reinterpret_cast<const float2*>(W2)[i];
  W2h[i] = __builtin_bit_cast(unsigned, __floats2half2_rn(b.x, b.y));
}

// ---------------- Xf2 [2048 bd][1025 r] -> Xf2T [1025 r][2048 bd] ----------
__global__ void xpose_xf(const unsigned* __restrict__ in, unsigned* __restrict__ out) {
  __shared__ unsigned tile[32][33];
  int c0 = blockIdx.x * 32;   // r
  int r0 = blockIdx.y * 32;   // bd
  int tx = threadIdx.x, ty = threadIdx.y;
  for (int i = ty; i < 32; i += 8) {
    int c = c0 + tx;
    tile[i][tx] = (c < RR) ? in[(size_t)(r0 + i) * RR + c] : 0u;
  }
  __syncthreads();
  for (int i = ty; i < 32; i += 8) {
    int c = c0 + i;
    if (c < RR) out[(size_t)c * 2048 + r0 + tx] = tile[tx][i];
  }
}

// ---------------- SfT [1025 r][256 h][16 n] -> SfN [2048 bh][1025 r] f2 -----
__global__ void xpose_sf(const float* __restrict__ in, float2* __restrict__ out) {
  __shared__ float tile[32][33];
  int r0 = blockIdx.x * 32;    // r
  int c0 = blockIdx.y * 32;    // hn
  int tx = threadIdx.x, ty = threadIdx.y;
  for (int i = ty; i < 32; i += 8) {
    int r = r0 + i;
    tile[i][tx] = (r < RR) ? in[(size_t)r * 4096 + c0 + tx] : 0.f;
  }
  __syncthreads();
  int r = r0 + tx;
  if (r < RR) {
    for (int p = ty; p < 16; p += 8) {
      int hn = c0 + 2 * p;
      int h = hn >> 4, n = hn & 15;
      int bh = (n >> 1) * 256 + h;
      out[(size_t)bh * RR + r] = make_float2(tile[tx][2 * p], tile[tx][2 * p + 1]);
    }
  }
}

// ---------------- Stockham radix-2 FFT, n=2048, in LDS ----------------
__device__ __forceinline__ float2* fft2048(float2* bufA, float2* bufB,
                                           const float2* __restrict__ tw, int t) {
  float2* src = bufA; float2* dst = bufB;
  for (int stage = 0; stage < 11; ++stage) {
    int s = 1 << stage;
    #pragma unroll
    for (int j = 0; j < 4; ++j) {
      int idx = t + 256 * j;
      int q = idx & (s - 1);
      int p = idx >> stage;
      float2 a = src[idx];
      float2 b = src[idx + 1024];
      float sr = a.x + b.x, si = a.y + b.y;
      float dr = a.x - b.x, di = a.y - b.y;
      float2 w = tw[p << stage];
      dst[q + 2 * s * p] = make_float2(sr, si);
      dst[q + 2 * s * p + s] = make_float2(dr * w.x - di * w.y, dr * w.y + di * w.x);
    }
    __syncthreads();
    float2* tmp = src; src = dst; dst = tmp;
  }
  return src;
}

__device__ __forceinline__ void build_tw(float2* tw, int t) {
  #pragma unroll
  for (int j = 0; j < 4; ++j) {
    int i = t + 256 * j;
    float xfrac = (float)i * (1.f / 1024.f);
    tw[i] = make_float2(cospif(xfrac), -sinpif(xfrac));
  }
}

// rfft -> packed f16 (re,im) per bin
__global__ void rfft_kernel(const float* __restrict__ z, unsigned* __restrict__ Xf2) {
  __shared__ float2 bufA[2048];
  __shared__ float2 bufB[2048];
  __shared__ float2 tw[1024];
  int row = blockIdx.x;
  int t = threadIdx.x;
  build_tw(tw, t);
  const float* zr = z + (size_t)row * LL;
  #pragma unroll
  for (int j = 0; j < 8; ++j) {
    int i = t + 256 * j;
    bufA[i] = make_float2(zr[i], 0.f);
  }
  __syncthreads();
  float2* res = fft2048(bufA, bufB, tw, t);
  #pragma unroll
  for (int j = 0; j < 5; ++j) {
    int r = t + 256 * j;
    if (r <= 1024) {
      float2 v = res[r];
      Xf2[(size_t)row * RR + r] = __builtin_bit_cast(unsigned, __floats2half2_rn(v.x, v.y));
    }
  }
}

// irfft(F, n=2048) = real( fft( conj(F_full) ) ) / 2048
__global__ void irfft_kernel(const float2* __restrict__ Sf, float* __restrict__ S) {
  __shared__ float2 bufA[2048];
  __shared__ float2 bufB[2048];
  __shared__ float2 tw[1024];
  int row = blockIdx.x;
  int t = threadIdx.x;
  build_tw(tw, t);
  const float2* fr = Sf + (size_t)row * RR;
  #pragma unroll
  for (int j = 0; j < 8; ++j) {
    int i = t + 256 * j;
    float2 v;
    if (i <= 1024) { v = fr[i]; v.y = -v.y; }
    else           { v = fr[2048 - i]; }
    bufA[i] = v;
  }
  __syncthreads();
  float2* res = fft2048(bufA, bufB, tw, t);
  const float scale = 1.f / 2048.f;
  float* sr = S + (size_t)row * LL;
  #pragma unroll
  for (int j = 0; j < 8; ++j) {
    int i = t + 256 * j;
    sr[i] = res[i].x * scale;
  }
}

// ---------------- spectral mixing as f16 MFMA GEMM (r19 + A-prefetch) ------
// 4 waves, grid (257,2); 128-kd phases; A fragments prefetched one full
// phase ahead into alternating named register sets (static indices only).
__global__ void __launch_bounds__(256)
spectral_mfma(const unsigned* __restrict__ Xf2T,       // [r][b*256+d] half2
              const unsigned short* __restrict__ A2,   // [h][6144] f16
              const float* __restrict__ Phi_re,
              const float* __restrict__ Phi_im,
              float* __restrict__ SfT) {               // [r][256 h][16 n]
  __shared__ unsigned xs_r[32][35];
  __shared__ unsigned xs_i[32][35];
  __shared__ alignas(16) unsigned Bl[2][64][68];
  __shared__ unsigned phi_pr[KK][4], phi_pi[KK][4];

  int t = threadIdx.x;
  int lane = t & 63;
  int w = t >> 6;
  int l15 = lane & 15;
  int l4 = lane >> 4;
  int r0 = blockIdx.x << 2;
  int h0 = blockIdx.y << 7;

  int bc = t & 31;
  int rq = t >> 5;             // 0..7
  int rl_b = rq >> 1;

  if (t < 96) {
    int k = t >> 2, rl = t & 3;
    int rc = min(r0 + rl, RR - 1);
    float pr = Phi_re[k * RR + rc], pi = Phi_im[k * RR + rc];
    phi_pr[k][rl] = __builtin_bit_cast(unsigned, __floats2half2_rn(pr, pr));
    phi_pi[k][rl] = __builtin_bit_cast(unsigned, __floats2half2_rn(pi, pi));
  }

  f32x4 acc[2][4];
  #pragma unroll
  for (int fm = 0; fm < 2; ++fm)
    #pragma unroll
    for (int fn = 0; fn < 4; ++fn) acc[fm][fn] = (f32x4){0.f, 0.f, 0.f, 0.f};

  const unsigned short* Arow0 = A2 + (size_t)(h0 + w * 32 + l15) * 6144 + l4 * 8;
  const unsigned short* Arow1 = Arow0 + (size_t)16 * 6144;

  #define SPEC_BUILD128(kk2, bbuf)                                             \
    {                                                                          \
      _Pragma("unroll")                                                        \
      for (int j_ = 0; j_ < 8; j_ += 2) {                                      \
        int b_ = ((rq & 1) << 2) + (j_ >> 1);                                  \
        unsigned xr_ = xs_r[bc][rl_b * 8 + b_];                                \
        unsigned xi_ = xs_i[bc][rl_b * 8 + b_];                                \
        __half2 xrh_ = __builtin_bit_cast(__half2, xr_);                       \
        __half2 xih_ = __builtin_bit_cast(__half2, xi_);                       \
        _Pragma("unroll")                                                      \
        for (int p_ = 0; p_ < 2; ++p_) {                                       \
          __half2 pr_ = __builtin_bit_cast(__half2, phi_pr[(kk2) + p_][rl_b]); \
          __half2 pi_ = __builtin_bit_cast(__half2, phi_pi[(kk2) + p_][rl_b]); \
          __half2 re_ = __hfma2(xrh_, pr_, __hmul2(xih_, pi_));                \
          __half2 im_ = __hfma2(xih_, pr_, __hneg2(__hmul2(xrh_, pi_)));       \
          Bl[bbuf][rq * 8 + j_][p_ * 32 + bc] = __builtin_bit_cast(unsigned, re_); \
          Bl[bbuf][rq * 8 + j_ + 1][p_ * 32 + bc] = __builtin_bit_cast(unsigned, im_); \
        }                                                                      \
      }                                                                        \
    }

  #define LOADA(D0, D1, PH)                                                    \
    {                                                                          \
      _Pragma("unroll")                                                        \
      for (int ks_ = 0; ks_ < 4; ++ks_) {                                      \
        size_t kcol_ = (size_t)(2 * (PH) + (ks_ >> 1)) * 256 + win * 64 +      \
                       (ks_ & 1) * 32;                                         \
        D0[ks_] = *reinterpret_cast<const f16x8*>(Arow0 + kcol_);              \
        D1[ks_] = *reinterpret_cast<const f16x8*>(Arow1 + kcol_);              \
      }                                                                        \
    }

  #define MFMA_ALL(A0, A1, BUF)                                                \
    {                                                                          \
      _Pragma("unroll")                                                        \
      for (int ks_ = 0; ks_ < 4; ++ks_) {                                      \
        _Pragma("unroll")                                                      \
        for (int fn_ = 0; fn_ < 4; ++fn_) {                                    \
          f16x8 bf_ = *reinterpret_cast<const f16x8*>(                         \
              &Bl[BUF][fn_ * 16 + l15][ks_ * 16 + l4 * 4]);                    \
          acc[0][fn_] = __builtin_amdgcn_mfma_f32_16x16x32_f16(A0[ks_], bf_,   \
                                                               acc[0][fn_], 0, 0, 0); \
          acc[1][fn_] = __builtin_amdgcn_mfma_f32_16x16x32_f16(A1[ks_], bf_,   \
                                                               acc[1][fn_], 0, 0, 0); \
        }                                                                      \
      }                                                                        \
    }

  f16x8 aC0[4], aC1[4], aN0[4], aN1[4];

  for (int win = 0; win < 4; ++win) {
    __syncthreads();
    // stage Xf window from Xf2T: coalesced uint2 per thread
    #pragma unroll
    for (int e = 0; e < 4; ++e) {
      int idx = t + 256 * e;           // 0..1023
      int rl = idx >> 8;               // 0..3
      int b  = (idx >> 5) & 7;
      int d2 = idx & 31;
      int rc = min(r0 + rl, RR - 1);
      const uint2 u = *reinterpret_cast<const uint2*>(
          Xf2T + (size_t)rc * 2048 + b * 256 + win * 64 + 2 * d2);
      xs_r[d2][rl * 8 + b] = (u.x & 0xffffu) | (u.y << 16);
      xs_i[d2][rl * 8 + b] = (u.x >> 16) | (u.y & 0xffff0000u);
    }
    __syncthreads();
    SPEC_BUILD128(0, 0);
    LOADA(aC0, aC1, 0);
    __syncthreads();
    #pragma unroll
    for (int phh = 0; phh < 6; ++phh) {
      const int ph = 2 * phh;
      // even phase ph: consume aC/buf0; prefetch ph+1 into aN, build buf1
      LOADA(aN0, aN1, ph + 1);
      SPEC_BUILD128(2 * (ph + 1), 1);
      MFMA_ALL(aC0, aC1, 0);
      __syncthreads();
      // odd phase ph+1: consume aN/buf1; prefetch ph+2 into aC, build buf0
      if (phh < 5) {
        LOADA(aC0, aC1, ph + 2);
        SPEC_BUILD128(2 * (ph + 2), 0);
      }
      MFMA_ALL(aN0, aN1, 1);
      __syncthreads();
    }
  }

  // epilogue: SfT[r][h][n], n = l15; coalesced 64B per 16 lanes
  #pragma unroll
  for (int fm = 0; fm < 2; ++fm)
    #pragma unroll
    for (int fn = 0; fn < 4; ++fn) {
      int r = min(r0 + fn, RR - 1);
      #pragma unroll
      for (int i = 0; i < 4; ++i) {
        int h = h0 + w * 32 + fm * 16 + l4 * 4 + i;
        SfT[((size_t)r * 256 + h) * 16 + l15] = acc[fm][fn][i];
      }
    }
  #undef SPEC_BUILD128
  #undef LOADA
  #undef MFMA_ALL
}

// ---------------- fused MLP as two f16 MFMA GEMMs + residual ----------------
__global__ void __launch_bounds__(256)
mlp_mfma(const float* __restrict__ S, const float* __restrict__ x,
         const unsigned short* __restrict__ W1h,   // [512][256] f16
         const float* __restrict__ b1,
         const unsigned short* __restrict__ W2h,   // [256][512] f16
         const float* __restrict__ b2,
         float* __restrict__ out) {
  __shared__ unsigned short S_lds[64 * 256];   // 32 KB, swizzled
  __shared__ unsigned short H_lds[64 * 128];   // 16 KB, swizzled
  char* Sb = reinterpret_cast<char*>(S_lds);
  char* Hb = reinterpret_cast<char*>(H_lds);

  int t = threadIdx.x;
  int lane = t & 63, w = t >> 6;
  int l15 = lane & 15, l4 = lane >> 4;
  int bb = blockIdx.x >> 5;
  int l0 = (blockIdx.x & 31) << 6;

  {
    int n = t & 63;
    int dbase = t >> 6;
    int n7s = (n & 7) << 4;
    const float* Sp = S + ((size_t)(bb * DD)) * LL + l0 + n;
    #pragma unroll 8
    for (int p = 0; p < 64; ++p) {
      int d = p * 4 + dbase;
      float v = Sp[(size_t)d * LL];
      *reinterpret_cast<unsigned short*>(Sb + n * 512 + ((2 * d) ^ n7s)) = f2h(v);
    }
  }

  f32x4 acc2[4][4];
  #pragma unroll
  for (int fm = 0; fm < 4; ++fm)
    #pragma unroll
    for (int fn = 0; fn < 4; ++fn) acc2[fm][fn] = (f32x4){0.f, 0.f, 0.f, 0.f};

  for (int ch = 0; ch < 4; ++ch) {
    __syncthreads();
    f32x4 acc1[2][4];
    #pragma unroll
    for (int fm = 0; fm < 2; ++fm) {
      float4 b1v = *reinterpret_cast<const float4*>(
          b1 + ch * 128 + w * 32 + fm * 16 + l4 * 4);
      #pragma unroll
      for (int fn = 0; fn < 4; ++fn)
        acc1[fm][fn] = (f32x4){b1v.x, b1v.y, b1v.z, b1v.w};
    }
    #pragma unroll
    for (int ks = 0; ks < 8; ++ks) {
      f16x8 af0 = *reinterpret_cast<const f16x8*>(
          W1h + (size_t)(ch * 128 + w * 32 + l15) * 256 + ks * 32 + l4 * 8);
      f16x8 af1 = *reinterpret_cast<const f16x8*>(
          W1h + (size_t)(ch * 128 + w * 32 + 16 + l15) * 256 + ks * 32 + l4 * 8);
      #pragma unroll
      for (int fn = 0; fn < 4; ++fn) {
        int n = fn * 16 + l15;
        f16x8 bf = *reinterpret_cast<const f16x8*>(
            Sb + n * 512 + ((64 * ks + 16 * l4) ^ ((n & 7) << 4)));
        acc1[0][fn] = __builtin_amdgcn_mfma_f32_16x16x32_f16(af0, bf, acc1[0][fn], 0, 0, 0);
        acc1[1][fn] = __builtin_amdgcn_mfma_f32_16x16x32_f16(af1, bf, acc1[1][fn], 0, 0, 0);
      }
    }
    #pragma unroll
    for (int fm = 0; fm < 2; ++fm)
      #pragma unroll
      for (int fn = 0; fn < 4; ++fn) {
        unsigned short hv[4];
        #pragma unroll
        for (int i = 0; i < 4; ++i) {
          float v = acc1[fm][fn][i];
          hv[i] = f2h(0.5f * v * (1.f + erff(v * 0.70710678118654752f)));
        }
        int n = fn * 16 + l15;
        int hl2 = 2 * (w * 32 + fm * 16 + l4 * 4);
        *reinterpret_cast<uint2*>(Hb + n * 256 + (hl2 ^ ((n & 7) << 4))) =
            *reinterpret_cast<uint2*>(hv);
      }
    __syncthreads();
    #pragma unroll
    for (int ks = 0; ks < 4; ++ks) {
      f16x8 bfv[4];
      #pragma unroll
      for (int fn = 0; fn < 4; ++fn) {
        int n = fn * 16 + l15;
        bfv[fn] = *reinterpret_cast<const f16x8*>(
            Hb + n * 256 + ((64 * ks + 16 * l4) ^ ((n & 7) << 4)));
      }
      #pragma unroll
      for (int fm = 0; fm < 4; ++fm) {
        f16x8 af = *reinterpret_cast<const f16x8*>(
            W2h + (size_t)(w * 64 + fm * 16 + l15) * 512 + ch * 128 + ks * 32 + l4 * 8);
        #pragma unroll
        for (int fn = 0; fn < 4; ++fn)
          acc2[fm][fn] = __builtin_amdgcn_mfma_f32_16x16x32_f16(af, bfv[fn], acc2[fm][fn], 0, 0, 0);
      }
    }
  }

  #pragma unroll
  for (int fm = 0; fm < 4; ++fm) {
    float4 b2v = *reinterpret_cast<const float4*>(b2 + w * 64 + fm * 16 + l4 * 4);
    #pragma unroll
    for (int i = 0; i < 4; ++i) {
      int d = w * 64 + fm * 16 + l4 * 4 + i;
      const float* xr = x + ((size_t)(bb * DD + d)) * LL + l0;
      float* orow = out + ((size_t)(bb * DD + d)) * LL + l0;
      float bias = (i == 0) ? b2v.x : (i == 1) ? b2v.y : (i == 2) ? b2v.z : b2v.w;
      #pragma unroll
      for (int fn = 0; fn < 4; ++fn) {
        int n = fn * 16 + l15;
        orow[n] = xr[n] + bias + acc2[fm][fn][i];
      }
    }
  }
}

extern "C" void kernel_launch(void* const* d_in, const int* in_sizes, int n_in,
                              void* d_out, int out_size, void* d_ws, size_t ws_size,
                              hipStream_t stream) {
  const float* x      = (const float*)d_in[0];
  const float* Phi_re = (const float*)d_in[1];
  const float* Phi_im = (const float*)d_in[2];
  const float* Theta  = (const float*)d_in[3];
  const float* gamma  = (const float*)d_in[4];
  const float* beta   = (const float*)d_in[5];
  const float* W1     = (const float*)d_in[6];
  const float* b1     = (const float*)d_in[7];
  const float* W2     = (const float*)d_in[8];
  const float* b2     = (const float*)d_in[9];

  float* ws = (float*)d_ws;
  float*    z    = ws;                            // [0, 4194304)
  unsigned* Xf2  = (unsigned*)(ws + 4194304);     // 2,099,200 u32
  unsigned* Xf2T = (unsigned*)(ws + 6293504);     // 2,099,200 u32
  float*    SfT  = ws + 8392704;                  // 4,198,400 f [r][h][n]
  float2*   SfN  = (float2*)(ws + 4194304);       // overlays Xf2+Xf2T (dead)
  unsigned* A2u  = (unsigned*)(ws + 12591104);    // 786,432 u32
  unsigned* W1h  = (unsigned*)(ws + 13377536);    // 65,536 u32
  unsigned* W2h  = (unsigned*)(ws + 13443072);    // 65,536 u32

  ln_kernel<<<dim3(BB * (LL / 64)), 256, 0, stream>>>(x, gamma, beta, z);
  theta_prep<<<dim3(KK * 256), 128, 0, stream>>>(Theta, A2u);
  w_prep<<<dim3(256), 256, 0, stream>>>(W1, W2, W1h, W2h);
  rfft_kernel<<<dim3(BB * DD), 256, 0, stream>>>(z, Xf2);
  xpose_xf<<<dim3(33, 64), dim3(32, 8), 0, stream>>>(Xf2, Xf2T);
  spectral_mfma<<<dim3(257, 2), 256, 0, stream>>>(
      Xf2T, (const unsigned short*)A2u, Phi_re, Phi_im, SfT);
  xpose_sf<<<dim3(33, 128), dim3(32, 8), 0, stream>>>(SfT, SfN);
  irfft_kernel<<<dim3(BB * DD), 256, 0, stream>>>(SfN, z);     // S -> z
  mlp_mfma<<<dim3(256), 256, 0, stream>>>(
      z, x, (const unsigned short*)W1h, b1, (const unsigned short*)W2h, b2,
      (float*)d_out);
}

// Round 21
// 232.617 us; speedup vs baseline: 1.0905x; 1.0905x over previous
//
#include <hip/hip_runtime.h>
#include <hip/hip_bf16.h>
#include <hip/hip_fp16.h>
#include <math.h>

#define BB 8
#define DD 256
#define LL 2048
#define KK 24
#define RR 1025
#define HH 512

typedef __attribute__((ext_vector_type(8))) _Float16 f16x8;
typedef __attribute__((ext_vector_type(4))) float f32x4;

__device__ __forceinline__ unsigned short f2h(float f) {
  return __builtin_bit_cast(unsigned short, __float2half_rn(f));
}

// ---------------- LayerNorm over channel dim D, per (b,l) ----------------
__global__ void ln_kernel(const float* __restrict__ x, const float* __restrict__ gamma,
                          const float* __restrict__ beta, float* __restrict__ z) {
  __shared__ float red[2][4][64];
  __shared__ float mu_s[64], rs_s[64];
  int blk = blockIdx.x;
  int b = blk >> 5;
  int l0 = (blk & 31) << 6;
  int t = threadIdx.x;
  int ll = t & 63;
  int part = t >> 6;
  int l = l0 + ll;
  const float* xb = x + ((size_t)b * DD) * LL + l;
  float xv[64];
  float s = 0.f, ss = 0.f;
  #pragma unroll
  for (int i = 0; i < 64; ++i) {
    float v = xb[(size_t)(part * 64 + i) * LL];
    xv[i] = v; s += v; ss += v * v;
  }
  red[0][part][ll] = s; red[1][part][ll] = ss;
  __syncthreads();
  if (part == 0) {
    float S = red[0][0][ll] + red[0][1][ll] + red[0][2][ll] + red[0][3][ll];
    float Q = red[1][0][ll] + red[1][1][ll] + red[1][2][ll] + red[1][3][ll];
    float mu = S * (1.f / 256.f);
    float var = Q * (1.f / 256.f) - mu * mu;
    mu_s[ll] = mu; rs_s[ll] = rsqrtf(var + 1e-5f);
  }
  __syncthreads();
  float mu = mu_s[ll], rs = rs_s[ll];
  float* zb = z + ((size_t)b * DD) * LL + l;
  #pragma unroll
  for (int i = 0; i < 64; ++i) {
    int d = part * 64 + i;
    zb[(size_t)d * LL] = (xv[i] - mu) * rs * gamma[d] + beta[d];
  }
}

// ---------------- Theta -> f16 A2[h][k*256+d] ----------------
__global__ void theta_prep(const float* __restrict__ Theta, unsigned* __restrict__ A2u) {
  int bi = blockIdx.x;
  int k = bi >> 8, h = bi & 255;
  int t = threadIdx.x;   // 0..127, d = 2t
  float2 v = *reinterpret_cast<const float2*>(Theta + (size_t)k * 65536 + h * 256 + 2 * t);
  A2u[(size_t)h * 3072 + k * 128 + t] =
      __builtin_bit_cast(unsigned, __floats2half2_rn(v.x, v.y));
}

// ---------------- W1/W2 -> f16 (same layouts) ----------------
__global__ void w_prep(const float* __restrict__ W1, const float* __restrict__ W2,
                       unsigned* __restrict__ W1h, unsigned* __restrict__ W2h) {
  int i = blockIdx.x * 256 + threadIdx.x;        // 0..65535, pairs
  float2 a = reinterpret_cast<const float2*>(W1)[i];
  W1h[i] = __builtin_bit_cast(unsigned, __floats2half2_rn(a.x, a.y));
  float2 b = reinterpret_cast<const float2*>(W2)[i];
  W2h[i] = __builtin_bit_cast(unsigned, __floats2half2_rn(b.x, b.y));
}

// ---------------- Xf2 [2048 bd][1025 r] -> Xf2T [1025 r][2048 bd] ----------
__global__ void xpose_xf(const unsigned* __restrict__ in, unsigned* __restrict__ out) {
  __shared__ unsigned tile[32][33];
  int c0 = blockIdx.x * 32;   // r
  int r0 = blockIdx.y * 32;   // bd
  int tx = threadIdx.x, ty = threadIdx.y;
  for (int i = ty; i < 32; i += 8) {
    int c = c0 + tx;
    tile[i][tx] = (c < RR) ? in[(size_t)(r0 + i) * RR + c] : 0u;
  }
  __syncthreads();
  for (int i = ty; i < 32; i += 8) {
    int c = c0 + i;
    if (c < RR) out[(size_t)c * 2048 + r0 + tx] = tile[tx][i];
  }
}

// ---------------- SfT [1025 r][256 h][16 n] -> SfN [2048 bh][1025 r] f2 -----
__global__ void xpose_sf(const float* __restrict__ in, float2* __restrict__ out) {
  __shared__ float tile[32][33];
  int r0 = blockIdx.x * 32;    // r
  int c0 = blockIdx.y * 32;    // hn
  int tx = threadIdx.x, ty = threadIdx.y;
  for (int i = ty; i < 32; i += 8) {
    int r = r0 + i;
    tile[i][tx] = (r < RR) ? in[(size_t)r * 4096 + c0 + tx] : 0.f;
  }
  __syncthreads();
  int r = r0 + tx;
  if (r < RR) {
    for (int p = ty; p < 16; p += 8) {
      int hn = c0 + 2 * p;
      int h = hn >> 4, n = hn & 15;
      int bh = (n >> 1) * 256 + h;
      out[(size_t)bh * RR + r] = make_float2(tile[tx][2 * p], tile[tx][2 * p + 1]);
    }
  }
}

// ---------------- Stockham radix-2 FFT, n=2048, in LDS ----------------
__device__ __forceinline__ float2* fft2048(float2* bufA, float2* bufB,
                                           const float2* __restrict__ tw, int t) {
  float2* src = bufA; float2* dst = bufB;
  for (int stage = 0; stage < 11; ++stage) {
    int s = 1 << stage;
    #pragma unroll
    for (int j = 0; j < 4; ++j) {
      int idx = t + 256 * j;
      int q = idx & (s - 1);
      int p = idx >> stage;
      float2 a = src[idx];
      float2 b = src[idx + 1024];
      float sr = a.x + b.x, si = a.y + b.y;
      float dr = a.x - b.x, di = a.y - b.y;
      float2 w = tw[p << stage];
      dst[q + 2 * s * p] = make_float2(sr, si);
      dst[q + 2 * s * p + s] = make_float2(dr * w.x - di * w.y, dr * w.y + di * w.x);
    }
    __syncthreads();
    float2* tmp = src; src = dst; dst = tmp;
  }
  return src;
}

__device__ __forceinline__ void build_tw(float2* tw, int t) {
  #pragma unroll
  for (int j = 0; j < 4; ++j) {
    int i = t + 256 * j;
    float xfrac = (float)i * (1.f / 1024.f);
    tw[i] = make_float2(cospif(xfrac), -sinpif(xfrac));
  }
}

// rfft of TWO real rows per block (rows 2q, 2q+1) via one complex FFT.
// A[r] = (F[r]+conj(F[m]))/2 ; B[r] = (F[r]-conj(F[m]))/(2i), m=(2048-r)&2047
__global__ void rfft_pair(const float* __restrict__ z, unsigned* __restrict__ Xf2) {
  __shared__ float2 bufA[2048];
  __shared__ float2 bufB[2048];
  __shared__ float2 tw[1024];
  int q = blockIdx.x;              // pair index 0..1023
  int t = threadIdx.x;
  build_tw(tw, t);
  const float* z0 = z + (size_t)(2 * q) * LL;
  const float* z1 = z0 + LL;
  #pragma unroll
  for (int j = 0; j < 8; ++j) {
    int i = t + 256 * j;
    bufA[i] = make_float2(z0[i], z1[i]);
  }
  __syncthreads();
  float2* res = fft2048(bufA, bufB, tw, t);
  unsigned* X0 = Xf2 + (size_t)(2 * q) * RR;
  unsigned* X1 = X0 + RR;
  #pragma unroll
  for (int j = 0; j < 5; ++j) {
    int r = t + 256 * j;
    if (r <= 1024) {
      int m = (2048 - r) & 2047;
      float2 Fr = res[r], Fm = res[m];
      float ax = 0.5f * (Fr.x + Fm.x), ay = 0.5f * (Fr.y - Fm.y);
      float bx = 0.5f * (Fr.y + Fm.y), by = -0.5f * (Fr.x - Fm.x);
      X0[r] = __builtin_bit_cast(unsigned, __floats2half2_rn(ax, ay));
      X1[r] = __builtin_bit_cast(unsigned, __floats2half2_rn(bx, by));
    }
  }
}

// inverse rfft of TWO hermitian rows per block -> two real rows.
// bufA[i<=1024] = (ar - bi, -ai - br); bufA[i>1024] = (ar_m + bi_m, ai_m - br_m)
// a = Re(fft(bufA))/2048 ; b = -Im(fft(bufA))/2048
__global__ void irfft_pair(const float2* __restrict__ Sf, float* __restrict__ S) {
  __shared__ float2 bufA[2048];
  __shared__ float2 bufB[2048];
  __shared__ float2 tw[1024];
  int q = blockIdx.x;              // pair index 0..1023
  int t = threadIdx.x;
  build_tw(tw, t);
  const float2* fa = Sf + (size_t)(2 * q) * RR;
  const float2* fb = fa + RR;
  #pragma unroll
  for (int j = 0; j < 8; ++j) {
    int i = t + 256 * j;
    float2 v;
    if (i <= 1024) {
      float2 a = fa[i], b = fb[i];
      v = make_float2(a.x - b.y, -a.y - b.x);
    } else {
      int m = 2048 - i;
      float2 a = fa[m], b = fb[m];
      v = make_float2(a.x + b.y, a.y - b.x);
    }
    bufA[i] = v;
  }
  __syncthreads();
  float2* res = fft2048(bufA, bufB, tw, t);
  const float scale = 1.f / 2048.f;
  float* s0 = S + (size_t)(2 * q) * LL;
  float* s1 = s0 + LL;
  #pragma unroll
  for (int j = 0; j < 8; ++j) {
    int i = t + 256 * j;
    s0[i] = res[i].x * scale;
    s1[i] = -res[i].y * scale;
  }
}

// ---------------- spectral mixing as f16 MFMA GEMM (r19, coalesced IO) -----
__global__ void __launch_bounds__(256)
spectral_mfma(const unsigned* __restrict__ Xf2T,       // [r][b*256+d] half2
              const unsigned short* __restrict__ A2,   // [h][6144] f16
              const float* __restrict__ Phi_re,
              const float* __restrict__ Phi_im,
              float* __restrict__ SfT) {               // [r][256 h][16 n]
  __shared__ unsigned xs_r[32][35];
  __shared__ unsigned xs_i[32][35];
  __shared__ alignas(16) unsigned Bl[2][64][68];
  __shared__ unsigned phi_pr[KK][4], phi_pi[KK][4];

  int t = threadIdx.x;
  int lane = t & 63;
  int w = t >> 6;
  int l15 = lane & 15;
  int l4 = lane >> 4;
  int r0 = blockIdx.x << 2;
  int h0 = blockIdx.y << 7;

  int bc = t & 31;
  int rq = t >> 5;             // 0..7
  int rl_b = rq >> 1;

  if (t < 96) {
    int k = t >> 2, rl = t & 3;
    int rc = min(r0 + rl, RR - 1);
    float pr = Phi_re[k * RR + rc], pi = Phi_im[k * RR + rc];
    phi_pr[k][rl] = __builtin_bit_cast(unsigned, __floats2half2_rn(pr, pr));
    phi_pi[k][rl] = __builtin_bit_cast(unsigned, __floats2half2_rn(pi, pi));
  }

  f32x4 acc[2][4];
  #pragma unroll
  for (int fm = 0; fm < 2; ++fm)
    #pragma unroll
    for (int fn = 0; fn < 4; ++fn) acc[fm][fn] = (f32x4){0.f, 0.f, 0.f, 0.f};

  const unsigned short* Arow0 = A2 + (size_t)(h0 + w * 32 + l15) * 6144 + l4 * 8;
  const unsigned short* Arow1 = Arow0 + (size_t)16 * 6144;

  #define SPEC_BUILD128(kk2, bbuf)                                             \
    {                                                                          \
      _Pragma("unroll")                                                        \
      for (int j_ = 0; j_ < 8; j_ += 2) {                                      \
        int b_ = ((rq & 1) << 2) + (j_ >> 1);                                  \
        unsigned xr_ = xs_r[bc][rl_b * 8 + b_];                                \
        unsigned xi_ = xs_i[bc][rl_b * 8 + b_];                                \
        __half2 xrh_ = __builtin_bit_cast(__half2, xr_);                       \
        __half2 xih_ = __builtin_bit_cast(__half2, xi_);                       \
        _Pragma("unroll")                                                      \
        for (int p_ = 0; p_ < 2; ++p_) {                                       \
          __half2 pr_ = __builtin_bit_cast(__half2, phi_pr[(kk2) + p_][rl_b]); \
          __half2 pi_ = __builtin_bit_cast(__half2, phi_pi[(kk2) + p_][rl_b]); \
          __half2 re_ = __hfma2(xrh_, pr_, __hmul2(xih_, pi_));                \
          __half2 im_ = __hfma2(xih_, pr_, __hneg2(__hmul2(xrh_, pi_)));       \
          Bl[bbuf][rq * 8 + j_][p_ * 32 + bc] = __builtin_bit_cast(unsigned, re_); \
          Bl[bbuf][rq * 8 + j_ + 1][p_ * 32 + bc] = __builtin_bit_cast(unsigned, im_); \
        }                                                                      \
      }                                                                        \
    }

  for (int win = 0; win < 4; ++win) {
    __syncthreads();
    #pragma unroll
    for (int e = 0; e < 4; ++e) {
      int idx = t + 256 * e;           // 0..1023
      int rl = idx >> 8;               // 0..3
      int b  = (idx >> 5) & 7;
      int d2 = idx & 31;
      int rc = min(r0 + rl, RR - 1);
      const uint2 u = *reinterpret_cast<const uint2*>(
          Xf2T + (size_t)rc * 2048 + b * 256 + win * 64 + 2 * d2);
      xs_r[d2][rl * 8 + b] = (u.x & 0xffffu) | (u.y << 16);
      xs_i[d2][rl * 8 + b] = (u.x >> 16) | (u.y & 0xffff0000u);
    }
    __syncthreads();
    SPEC_BUILD128(0, 0);
    __syncthreads();
    for (int ph = 0; ph < 12; ++ph) {
      const int buf = ph & 1;
      if (ph < 11) SPEC_BUILD128(2 * (ph + 1), buf ^ 1);
      #pragma unroll
      for (int ks = 0; ks < 4; ++ks) {
        size_t kcol = (size_t)(2 * ph + (ks >> 1)) * 256 + win * 64 + (ks & 1) * 32;
        f16x8 a0 = *reinterpret_cast<const f16x8*>(Arow0 + kcol);
        f16x8 a1 = *reinterpret_cast<const f16x8*>(Arow1 + kcol);
        #pragma unroll
        for (int fn = 0; fn < 4; ++fn) {
          f16x8 bf = *reinterpret_cast<const f16x8*>(
              &Bl[buf][fn * 16 + l15][ks * 16 + l4 * 4]);
          acc[0][fn] = __builtin_amdgcn_mfma_f32_16x16x32_f16(a0, bf, acc[0][fn], 0, 0, 0);
          acc[1][fn] = __builtin_amdgcn_mfma_f32_16x16x32_f16(a1, bf, acc[1][fn], 0, 0, 0);
        }
      }
      __syncthreads();
    }
  }

  #pragma unroll
  for (int fm = 0; fm < 2; ++fm)
    #pragma unroll
    for (int fn = 0; fn < 4; ++fn) {
      int r = min(r0 + fn, RR - 1);
      #pragma unroll
      for (int i = 0; i < 4; ++i) {
        int h = h0 + w * 32 + fm * 16 + l4 * 4 + i;
        SfT[((size_t)r * 256 + h) * 16 + l15] = acc[fm][fn][i];
      }
    }
  #undef SPEC_BUILD128
}

// ---------------- fused MLP as two f16 MFMA GEMMs + residual ----------------
__global__ void __launch_bounds__(256)
mlp_mfma(const float* __restrict__ S, const float* __restrict__ x,
         const unsigned short* __restrict__ W1h,   // [512][256] f16
         const float* __restrict__ b1,
         const unsigned short* __restrict__ W2h,   // [256][512] f16
         const float* __restrict__ b2,
         float* __restrict__ out) {
  __shared__ unsigned short S_lds[64 * 256];   // 32 KB, swizzled
  __shared__ unsigned short H_lds[64 * 128];   // 16 KB, swizzled
  char* Sb = reinterpret_cast<char*>(S_lds);
  char* Hb = reinterpret_cast<char*>(H_lds);

  int t = threadIdx.x;
  int lane = t & 63, w = t >> 6;
  int l15 = lane & 15, l4 = lane >> 4;
  int bb = blockIdx.x >> 5;
  int l0 = (blockIdx.x & 31) << 6;

  {
    int n = t & 63;
    int dbase = t >> 6;
    int n7s = (n & 7) << 4;
    const float* Sp = S + ((size_t)(bb * DD)) * LL + l0 + n;
    #pragma unroll 8
    for (int p = 0; p < 64; ++p) {
      int d = p * 4 + dbase;
      float v = Sp[(size_t)d * LL];
      *reinterpret_cast<unsigned short*>(Sb + n * 512 + ((2 * d) ^ n7s)) = f2h(v);
    }
  }

  f32x4 acc2[4][4];
  #pragma unroll
  for (int fm = 0; fm < 4; ++fm)
    #pragma unroll
    for (int fn = 0; fn < 4; ++fn) acc2[fm][fn] = (f32x4){0.f, 0.f, 0.f, 0.f};

  for (int ch = 0; ch < 4; ++ch) {
    __syncthreads();
    f32x4 acc1[2][4];
    #pragma unroll
    for (int fm = 0; fm < 2; ++fm) {
      float4 b1v = *reinterpret_cast<const float4*>(
          b1 + ch * 128 + w * 32 + fm * 16 + l4 * 4);
      #pragma unroll
      for (int fn = 0; fn < 4; ++fn)
        acc1[fm][fn] = (f32x4){b1v.x, b1v.y, b1v.z, b1v.w};
    }
    #pragma unroll
    for (int ks = 0; ks < 8; ++ks) {
      f16x8 af0 = *reinterpret_cast<const f16x8*>(
          W1h + (size_t)(ch * 128 + w * 32 + l15) * 256 + ks * 32 + l4 * 8);
      f16x8 af1 = *reinterpret_cast<const f16x8*>(
          W1h + (size_t)(ch * 128 + w * 32 + 16 + l15) * 256 + ks * 32 + l4 * 8);
      #pragma unroll
      for (int fn = 0; fn < 4; ++fn) {
        int n = fn * 16 + l15;
        f16x8 bf = *reinterpret_cast<const f16x8*>(
            Sb + n * 512 + ((64 * ks + 16 * l4) ^ ((n & 7) << 4)));
        acc1[0][fn] = __builtin_amdgcn_mfma_f32_16x16x32_f16(af0, bf, acc1[0][fn], 0, 0, 0);
        acc1[1][fn] = __builtin_amdgcn_mfma_f32_16x16x32_f16(af1, bf, acc1[1][fn], 0, 0, 0);
      }
    }
    #pragma unroll
    for (int fm = 0; fm < 2; ++fm)
      #pragma unroll
      for (int fn = 0; fn < 4; ++fn) {
        unsigned short hv[4];
        #pragma unroll
        for (int i = 0; i < 4; ++i) {
          float v = acc1[fm][fn][i];
          hv[i] = f2h(0.5f * v * (1.f + erff(v * 0.70710678118654752f)));
        }
        int n = fn * 16 + l15;
        int hl2 = 2 * (w * 32 + fm * 16 + l4 * 4);
        *reinterpret_cast<uint2*>(Hb + n * 256 + (hl2 ^ ((n & 7) << 4))) =
            *reinterpret_cast<uint2*>(hv);
      }
    __syncthreads();
    #pragma unroll
    for (int ks = 0; ks < 4; ++ks) {
      f16x8 bfv[4];
      #pragma unroll
      for (int fn = 0; fn < 4; ++fn) {
        int n = fn * 16 + l15;
        bfv[fn] = *reinterpret_cast<const f16x8*>(
            Hb + n * 256 + ((64 * ks + 16 * l4) ^ ((n & 7) << 4)));
      }
      #pragma unroll
      for (int fm = 0; fm < 4; ++fm) {
        f16x8 af = *reinterpret_cast<const f16x8*>(
            W2h + (size_t)(w * 64 + fm * 16 + l15) * 512 + ch * 128 + ks * 32 + l4 * 8);
        #pragma unroll
        for (int fn = 0; fn < 4; ++fn)
          acc2[fm][fn] = __builtin_amdgcn_mfma_f32_16x16x32_f16(af, bfv[fn], acc2[fm][fn], 0, 0, 0);
      }
    }
  }

  #pragma unroll
  for (int fm = 0; fm < 4; ++fm) {
    float4 b2v = *reinterpret_cast<const float4*>(b2 + w * 64 + fm * 16 + l4 * 4);
    #pragma unroll
    for (int i = 0; i < 4; ++i) {
      int d = w * 64 + fm * 16 + l4 * 4 + i;
      const float* xr = x + ((size_t)(bb * DD + d)) * LL + l0;
      float* orow = out + ((size_t)(bb * DD + d)) * LL + l0;
      float bias = (i == 0) ? b2v.x : (i == 1) ? b2v.y : (i == 2) ? b2v.z : b2v.w;
      #pragma unroll
      for (int fn = 0; fn < 4; ++fn) {
        int n = fn * 16 + l15;
        orow[n] = xr[n] + bias + acc2[fm][fn][i];
      }
    }
  }
}

extern "C" void kernel_launch(void* const* d_in, const int* in_sizes, int n_in,
                              void* d_out, int out_size, void* d_ws, size_t ws_size,
                              hipStream_t stream) {
  const float* x      = (const float*)d_in[0];
  const float* Phi_re = (const float*)d_in[1];
  const float* Phi_im = (const float*)d_in[2];
  const float* Theta  = (const float*)d_in[3];
  const float* gamma  = (const float*)d_in[4];
  const float* beta   = (const float*)d_in[5];
  const float* W1     = (const float*)d_in[6];
  const float* b1     = (const float*)d_in[7];
  const float* W2     = (const float*)d_in[8];
  const float* b2     = (const float*)d_in[9];

  float* ws = (float*)d_ws;
  float*    z    = ws;                            // [0, 4194304)
  unsigned* Xf2  = (unsigned*)(ws + 4194304);     // 2,099,200 u32
  unsigned* Xf2T = (unsigned*)(ws + 6293504);     // 2,099,200 u32
  float*    SfT  = ws + 8392704;                  // 4,198,400 f [r][h][n]
  float2*   SfN  = (float2*)(ws + 4194304);       // overlays Xf2+Xf2T (dead)
  unsigned* A2u  = (unsigned*)(ws + 12591104);    // 786,432 u32
  unsigned* W1h  = (unsigned*)(ws + 13377536);    // 65,536 u32
  unsigned* W2h  = (unsigned*)(ws + 13443072);    // 65,536 u32

  ln_kernel<<<dim3(BB * (LL / 64)), 256, 0, stream>>>(x, gamma, beta, z);
  theta_prep<<<dim3(KK * 256), 128, 0, stream>>>(Theta, A2u);
  w_prep<<<dim3(256), 256, 0, stream>>>(W1, W2, W1h, W2h);
  rfft_pair<<<dim3(BB * DD / 2), 256, 0, stream>>>(z, Xf2);
  xpose_xf<<<dim3(33, 64), dim3(32, 8), 0, stream>>>(Xf2, Xf2T);
  spectral_mfma<<<dim3(257, 2), 256, 0, stream>>>(
      Xf2T, (const unsigned short*)A2u, Phi_re, Phi_im, SfT);
  xpose_sf<<<dim3(33, 128), dim3(32, 8), 0, stream>>>(SfT, SfN);
  irfft_pair<<<dim3(BB * DD / 2), 256, 0, stream>>>(SfN, z);   // S -> z
  mlp_mfma<<<dim3(256), 256, 0, stream>>>(
      z, x, (const unsigned short*)W1h, b1, (const unsigned short*)W2h, b2,
      (float*)d_out);
}